// Round 10
// baseline (132.128 us; speedup 1.0000x reference)
//
#include <hip/hip_runtime.h>

#define NB 8
#define N1 8192
#define N2 2048
#define C1 256
#define C2 512
#define CO 768   // C1 + C2
#define CCH 4    // channels per interp block

// ws: keys4 (B*N2 float4 = 256 KB) | nn_idx (B*N1*4 ints = 1 MB) |
//     nn_w (B*N1*4 floats = 1 MB). Total 2.25 MB.

// ---------------------------------------------------------------------------
// ASM-PINNED arithmetic (R8-validated bit sequence):
//   nrm2 = (x*x + y*y) + z*z            (stepwise rn)
//   dot  = fma(z,qz, fma(y,qy, x*qx))   (fma chain)
//   d2   = (qq + kk) - 2*dot            (stepwise rn)
// D2PIN_S: identical instruction sequence, key operands sourced from SGPRs
// (src0 slot — legal for VOP2; 1 SGPR per VOP3 fma). Multiplication operand
// order swap is IEEE-exact-commutative => d2 bits unchanged vs R8.
// ---------------------------------------------------------------------------
#define NRM2(X, Y, Z) ({                                                   \
    float _s, _t;                                                          \
    asm("v_mul_f32 %0, %2, %2\n\t"                                         \
        "v_mul_f32 %1, %3, %3\n\t"                                         \
        "v_add_f32 %0, %0, %1\n\t"                                         \
        "v_mul_f32 %1, %4, %4\n\t"                                         \
        "v_add_f32 %0, %0, %1"                                             \
        : "=&v"(_s), "=&v"(_t) : "v"(X), "v"(Y), "v"(Z));                  \
    _s; })

#define D2PIN_S(QX, QY, QZ, QQ, SX, SY, SZ, SKK) ({                        \
    float _d, _t;                                                          \
    asm("v_mul_f32 %0, %5, %2\n\t"        /* kx*qx (src0=sgpr)      */     \
        "v_fma_f32 %0, %6, %3, %0\n\t"    /* + ky*qy (single-round) */     \
        "v_fma_f32 %0, %7, %4, %0\n\t"    /* + kz*qz (single-round) */     \
        "v_add_f32 %1, %9, %8\n\t"        /* kk+qq                  */     \
        "v_mul_f32 %0, 2.0, %0\n\t"       /* 2*dot                  */     \
        "v_sub_f32 %0, %1, %0"            /* d2                     */     \
        : "=&v"(_d), "=&v"(_t)                                             \
        : "v"(QX), "v"(QY), "v"(QZ), "s"(SX), "s"(SY), "s"(SZ),            \
          "v"(QQ), "s"(SKK));                                              \
    _d; })

// ---------------------------------------------------------------------------
// Pack keys to float4(x,y,z,|k|^2) in global ws. NRM2 asm-pinned -> kk bits
// identical to the R8-validated in-kernel computation.
// ---------------------------------------------------------------------------
__global__ __launch_bounds__(256) void pack_keys(
    const float* __restrict__ kxyz,   // (B, 3, N2)
    float4* __restrict__ keys4)       // (B, N2)
{
    const int b = blockIdx.x >> 3;
    const int j = (blockIdx.x & 7) * 256 + threadIdx.x;
    const float* kb = kxyz + (size_t)b * 3 * N2;
    float x = kb[j], y = kb[N2 + j], z = kb[2 * N2 + j];
    keys4[(size_t)b * N2 + j] = make_float4(x, y, z, NRM2(x, y, z));
}

// ---------------------------------------------------------------------------
// KNN scan via the SCALAR path. Block = 64 queries x 8 waves; wave w scans
// keys [w*256,(w+1)*256) ascending. Key quad (x,y,z,kk) is wave-uniform ->
// compiler emits s_load (sK$), freeing both the LDS pipe (R8's 41us
// bottleneck) and vL1. Lane = query. Chunk-local sorted top-3 merged by
// tid<64 in (chunk asc, rank asc) order with strict-< => selection identical
// to a single ascending scan == jax.lax.top_k (validated R8 logic, 8 chunks).
// qfeat->out copy folded in: this kernel is VALU-bound with idle HBM.
// ---------------------------------------------------------------------------
__global__ __launch_bounds__(512) void knn_scan(
    const float* __restrict__ qxyz,   // (B, 3, N1)
    const float4* __restrict__ keys4, // (B, N2) packed
    const float* __restrict__ qfeat,  // (B, C1, N1)
    int*   __restrict__ nn_idx,       // (B*N1*4) packed
    float* __restrict__ nn_w,         // (B*N1*4) packed
    float* __restrict__ out)          // (B, CO, N1)
{
    __shared__ float pd[8][64][3];     // 6 KB
    __shared__ int   pi[8][64][3];     // 6 KB

    const int b    = blockIdx.x >> 7;       // 128 tiles of 64 queries
    const int tile = blockIdx.x & 127;
    const int n0   = tile * 64;
    const int tid  = threadIdx.x;
    const int w    = tid >> 6, lane = tid & 63;

    const int n = n0 + lane;
    const float* qb = qxyz + (size_t)b * 3 * N1;
    const float qx = qb[n], qy = qb[N1 + n], qz = qb[2 * N1 + n];
    const float qq = NRM2(qx, qy, qz);

    float b0 = 3.4e38f, b1 = 3.4e38f, b2 = 3.4e38f;
    int   i0 = 0, i1 = 0, i2 = 0;

#define PROC(X, Y, Z, KK, J) do {                                          \
        float d2 = D2PIN_S(qx, qy, qz, qq, (X), (Y), (Z), (KK));           \
        if (d2 < b2) {                                                     \
            bool c0 = d2 < b0, c1 = d2 < b1;                               \
            b2 = c1 ? b1 : d2;               i2 = c1 ? i1 : (J);           \
            b1 = c0 ? b0 : (c1 ? d2 : b1);   i1 = c0 ? i0 : (c1 ? (J) : i1); \
            b0 = c0 ? d2 : b0;               i0 = c0 ? (J) : i0;           \
        }                                                                  \
    } while (0)

    const float4* kb4 = keys4 + (size_t)b * N2;
    const int jlo = w * (N2 / 8);            // 256 keys per wave
    #pragma unroll 8
    for (int u = 0; u < N2 / 8; ++u) {
        const float4 k4 = kb4[jlo + u];      // wave-uniform -> s_load
        PROC(k4.x, k4.y, k4.z, k4.w, jlo + u);
    }
#undef PROC

    pd[w][lane][0] = b0; pd[w][lane][1] = b1; pd[w][lane][2] = b2;
    pi[w][lane][0] = i0; pi[w][lane][1] = i1; pi[w][lane][2] = i2;
    __syncthreads();

    if (tid < 64) {
        float m0 = 3.4e38f, m1 = 3.4e38f, m2 = 3.4e38f;
        int   j0 = 0, j1 = 0, j2 = 0;
        #pragma unroll
        for (int c = 0; c < 8; ++c) {
            #pragma unroll
            for (int s = 0; s < 3; ++s) {
                float d = pd[c][tid][s];
                int   i = pi[c][tid][s];
                if (d < m2) {
                    bool c0 = d < m0, c1 = d < m1;
                    m2 = c1 ? m1 : d;                j2 = c1 ? j1 : i;
                    m1 = c0 ? m0 : (c1 ? d : m1);    j1 = c0 ? j0 : (c1 ? i : j1);
                    m0 = c0 ? d : m0;                j0 = c0 ? i  : j0;
                }
            }
        }
        // weights: mirror reference op order (R8-validated, packed store)
        float d0f = fmaxf(m0, 1e-10f), d1f = fmaxf(m1, 1e-10f), d2f = fmaxf(m2, 1e-10f);
        float v0 = __fdiv_rn(1.0f, d0f), v1 = __fdiv_rn(1.0f, d1f), v2 = __fdiv_rn(1.0f, d2f);
        float s  = __fadd_rn(__fadd_rn(v0, v1), v2);
        const size_t g = (size_t)b * N1 + n0 + tid;
        *(int4*)  &nn_idx[g * 4] = make_int4(j0, j1, j2, 0);
        *(float4*)&nn_w  [g * 4] = make_float4(__fdiv_rn(v0, s), __fdiv_rn(v1, s),
                                               __fdiv_rn(v2, s), 0.0f);
    }

    // Folded qfeat copy (validated float4 stream; overlaps idle HBM).
    // Per block: float4s [tile*4096, (tile+1)*4096) of this batch's plane.
    const float4* qsrc = (const float4*)(qfeat + (size_t)b * C1 * N1);
    float4*       qdst = (float4*)(out + (size_t)b * CO * N1 + (size_t)C2 * N1);
    #pragma unroll
    for (int k = 0; k < 8; ++k) {
        const size_t r = (size_t)tile * 4096 + (size_t)k * 512 + tid;
        qdst[r] = qsrc[r];
    }
}

// ---------------------------------------------------------------------------
// Interp (R9-validated minus the copy tail). Block = (batch, 4-channel
// group); 4 channels staged as float4-per-key in LDS (32 KB); gather =
// 3 ds_read_b128; nn loads coalesced int4/float4. fma order validated.
// ---------------------------------------------------------------------------
__global__ __launch_bounds__(256) void interp4(
    const float* __restrict__ kfeat,  // (B, C2, N2)
    const int*   __restrict__ nn_idx, // packed stride-4
    const float* __restrict__ nn_w,   // packed stride-4
    float* __restrict__ out)          // (B, CO, N1)
{
    __shared__ __align__(16) float4 skf[N2];   // 32 KB
    const int b     = blockIdx.x & 7;       // XCD-pinned batch
    const int cg    = blockIdx.x >> 3;      // 0..127
    const int cbase = cg * CCH;
    const int tid   = threadIdx.x;

    const float* kf = kfeat + (size_t)b * C2 * N2 + (size_t)cbase * N2;
    for (int j = tid; j < N2; j += 256) {
        skf[j] = make_float4(kf[j], kf[N2 + j], kf[2 * N2 + j], kf[3 * N2 + j]);
    }
    __syncthreads();

    const int*   ib = nn_idx + (size_t)b * N1 * 4;
    const float* wb = nn_w   + (size_t)b * N1 * 4;
    float* ob = out + (size_t)b * CO * N1;

    #pragma unroll 4
    for (int t = 0; t < N1 / 256; ++t) {
        const int n = t * 256 + tid;
        const int4   iv = *(const int4*)  &ib[(size_t)n * 4];
        const float4 wv = *(const float4*)&wb[(size_t)n * 4];
        const float4 f0 = skf[iv.x];
        const float4 f1 = skf[iv.y];
        const float4 f2 = skf[iv.z];
        ob[(size_t)(cbase + 0) * N1 + n] =
            fmaf(wv.z, f2.x, fmaf(wv.y, f1.x, __fmul_rn(wv.x, f0.x)));
        ob[(size_t)(cbase + 1) * N1 + n] =
            fmaf(wv.z, f2.y, fmaf(wv.y, f1.y, __fmul_rn(wv.x, f0.y)));
        ob[(size_t)(cbase + 2) * N1 + n] =
            fmaf(wv.z, f2.z, fmaf(wv.y, f1.z, __fmul_rn(wv.x, f0.z)));
        ob[(size_t)(cbase + 3) * N1 + n] =
            fmaf(wv.z, f2.w, fmaf(wv.y, f1.w, __fmul_rn(wv.x, f0.w)));
    }
}

extern "C" void kernel_launch(void* const* d_in, const int* in_sizes, int n_in,
                              void* d_out, int out_size, void* d_ws, size_t ws_size,
                              hipStream_t stream) {
    const float* qxyz  = (const float*)d_in[0];
    const float* kxyz  = (const float*)d_in[1];
    const float* qfeat = (const float*)d_in[2];
    const float* kfeat = (const float*)d_in[3];
    float* out = (float*)d_out;

    float*  ws     = (float*)d_ws;
    float4* keys4  = (float4*)ws;                                // 65536 f
    int*    nn_idx = (int*)(ws + (size_t)4 * NB * N2);           // 262144 i
    float*  nn_w   = ws + (size_t)4 * NB * N2 + (size_t)4 * NB * N1;

    pack_keys<<<NB * (N2 / 256), 256, 0, stream>>>(kxyz, keys4);
    knn_scan<<<NB * (N1 / 64), 512, 0, stream>>>(qxyz, keys4, qfeat,
                                                 nn_idx, nn_w, out);
    interp4<<<NB * (C2 / CCH), 256, 0, stream>>>(kfeat, nn_idx, nn_w, out);
}

// Round 11
// 112.301 us; speedup vs baseline: 1.1765x; 1.1765x over previous
//
#include <hip/hip_runtime.h>

#define NB 8
#define N1 8192
#define N2 2048
#define C1 256
#define C2 512
#define CO 768   // C1 + C2
#define CCH 4    // channels per interp block

typedef float f2 __attribute__((ext_vector_type(2)));
typedef float f4 __attribute__((ext_vector_type(4)));

// ws: keys4 (B*N2 float4 = 256 KB) | nn_idx (B*N1*4 ints = 1 MB) |
//     nn_w (B*N1*4 floats = 1 MB). Total 2.25 MB.

// ---------------------------------------------------------------------------
// ASM-PINNED arithmetic (R8-validated bit sequence):
//   nrm2 = (x*x + y*y) + z*z            (stepwise rn)
//   dot  = fma(z,qz, fma(y,qy, x*qx))   (fma chain)
//   d2   = (qq + kk) - 2*dot            (stepwise rn)
// PKD2: packed-pair variant (2 keys per sequence). Bit-equivalence proof:
//  - each v_pk_* half is an independent IEEE-rn op == scalar op;
//  - operand order swaps (kx*qx, kk+qq) are exact-commutative;
//  - 2*dot is exact (exponent shift) => sub(s,2*dot) and fma(dot,-2,s) are
//    both one rounding of the same real number => identical bits.
// ---------------------------------------------------------------------------
#define NRM2(X, Y, Z) ({                                                   \
    float _s, _t;                                                          \
    asm("v_mul_f32 %0, %2, %2\n\t"                                         \
        "v_mul_f32 %1, %3, %3\n\t"                                         \
        "v_add_f32 %0, %0, %1\n\t"                                         \
        "v_mul_f32 %1, %4, %4\n\t"                                         \
        "v_add_f32 %0, %0, %1"                                             \
        : "=&v"(_s), "=&v"(_t) : "v"(X), "v"(Y), "v"(Z));                  \
    _s; })

#define PKD2(X01, Y01, Z01, K01, QXD, QYD, QZD, QQD, M2) ({                \
    f2 _d, _s;                                                             \
    asm("v_pk_mul_f32 %0, %2, %6\n\t"      /* kx*qx per half        */     \
        "v_pk_fma_f32 %0, %3, %7, %0\n\t"  /* + ky*qy               */     \
        "v_pk_fma_f32 %0, %4, %8, %0\n\t"  /* + kz*qz -> dot        */     \
        "v_pk_add_f32 %1, %5, %9\n\t"      /* kk+qq                 */     \
        "v_pk_fma_f32 %0, %0, %10, %1"     /* d2 = dot*(-2)+(kk+qq) */     \
        : "=&v"(_d), "=&v"(_s)                                             \
        : "v"(X01), "v"(Y01), "v"(Z01), "v"(K01),                          \
          "v"(QXD), "v"(QYD), "v"(QZD), "v"(QQD), "v"(M2));                \
    _d; })

// Branchy top-3 insert, validated R0/R8 structure; S = query-state suffix.
#define INS(S, D2, J) do {                                                 \
        float _v = (D2);                                                   \
        if (_v < b2##S) {                                                  \
            bool c0 = _v < b0##S, c1 = _v < b1##S;                         \
            b2##S = c1 ? b1##S : _v;                                       \
            i2##S = c1 ? i1##S : (J);                                      \
            b1##S = c0 ? b0##S : (c1 ? _v : b1##S);                        \
            i1##S = c0 ? i0##S : (c1 ? (J) : i1##S);                       \
            b0##S = c0 ? _v : b0##S;                                       \
            i0##S = c0 ? (J) : i0##S;                                      \
        } } while (0)

// ---------------------------------------------------------------------------
// Pack keys to float4(x,y,z,|k|^2) in global ws (R9/R10-validated).
// ---------------------------------------------------------------------------
__global__ __launch_bounds__(256) void pack_keys(
    const float* __restrict__ kxyz,   // (B, 3, N2)
    float4* __restrict__ keys4)       // (B, N2)
{
    const int b = blockIdx.x >> 3;
    const int j = (blockIdx.x & 7) * 256 + threadIdx.x;
    const float* kb = kxyz + (size_t)b * 3 * N2;
    float x = kb[j], y = kb[N2 + j], z = kb[2 * N2 + j];
    keys4[(size_t)b * N2 + j] = make_float4(x, y, z, NRM2(x, y, z));
}

// ---------------------------------------------------------------------------
// KNN: block = 512 thr = 8 waves = 128 queries (2 per lane: qa=n0+lane,
// qb=n0+64+lane). Keys staged once to LDS SoA (skx/sky/skz/skk). Wave w
// scans chunk [w*256,(w+1)*256) ascending; each key-broadcast (b128 over 4
// keys per array) now serves BOTH queries -> LDS-pipe cost halves vs R8.
// d2 via packed-pair PKD2 (bit-identical, see proof above); selection =
// validated branchy insert per query, ascending j. 8-chunk merge by
// tid<128 in (chunk asc, rank asc) order with strict-< (R10-validated) ==
// single ascending scan == jax.lax.top_k. qfeat copy folded (R9/R10).
// ---------------------------------------------------------------------------
__global__ __launch_bounds__(512, 4) void knn_scan(
    const float* __restrict__ qxyz,   // (B, 3, N1)
    const float4* __restrict__ keys4, // (B, N2) packed
    const float* __restrict__ qfeat,  // (B, C1, N1)
    int*   __restrict__ nn_idx,       // (B*N1*4) packed
    float* __restrict__ nn_w,         // (B*N1*4) packed
    float* __restrict__ out)          // (B, CO, N1)
{
    __shared__ __align__(16) float skx[N2];
    __shared__ __align__(16) float sky[N2];
    __shared__ __align__(16) float skz[N2];
    __shared__ __align__(16) float skk[N2];
    __shared__ float pd[8][128][3];    // 12 KB
    __shared__ int   pi[8][128][3];    // 12 KB

    const int b    = blockIdx.x >> 6;       // 64 tiles of 128 queries
    const int tile = blockIdx.x & 63;
    const int n0   = tile * 128;
    const int tid  = threadIdx.x;
    const int w    = tid >> 6, lane = tid & 63;

    // stage keys (coalesced float4 from packed ws; values bit-identical)
    const float4* kb4 = keys4 + (size_t)b * N2;
    for (int j = tid; j < N2; j += 512) {
        float4 k4 = kb4[j];
        skx[j] = k4.x; sky[j] = k4.y; skz[j] = k4.z; skk[j] = k4.w;
    }
    __syncthreads();

    // two queries per lane
    const int na = n0 + lane, nb = n0 + 64 + lane;
    const float* qb = qxyz + (size_t)b * 3 * N1;
    const float qxA = qb[na], qyA = qb[N1 + na], qzA = qb[2 * N1 + na];
    const float qxB = qb[nb], qyB = qb[N1 + nb], qzB = qb[2 * N1 + nb];
    const float qqA = NRM2(qxA, qyA, qzA);
    const float qqB = NRM2(qxB, qyB, qzB);

    f2 qxdA, qydA, qzdA, qqdA, qxdB, qydB, qzdB, qqdB, m2;
    qxdA.x = qxA; qxdA.y = qxA;  qydA.x = qyA; qydA.y = qyA;
    qzdA.x = qzA; qzdA.y = qzA;  qqdA.x = qqA; qqdA.y = qqA;
    qxdB.x = qxB; qxdB.y = qxB;  qydB.x = qyB; qydB.y = qyB;
    qzdB.x = qzB; qzdB.y = qzB;  qqdB.x = qqB; qqdB.y = qqB;
    m2.x = -2.0f; m2.y = -2.0f;

    float b0A = 3.4e38f, b1A = 3.4e38f, b2A = 3.4e38f;
    float b0B = 3.4e38f, b1B = 3.4e38f, b2B = 3.4e38f;
    int   i0A = 0, i1A = 0, i2A = 0, i0B = 0, i1B = 0, i2B = 0;

    const int jlo = w * (N2 / 8);            // 256 keys per wave-chunk
    #pragma unroll 4
    for (int g = 0; g < (N2 / 8) / 4; ++g) {
        const int jb = jlo + g * 4;
        f4 x4 = *(const f4*)&skx[jb];        // wave-uniform b128 broadcast
        f4 y4 = *(const f4*)&sky[jb];
        f4 z4 = *(const f4*)&skz[jb];
        f4 k4 = *(const f4*)&skk[jb];
        f2 dA01 = PKD2(x4.xy, y4.xy, z4.xy, k4.xy, qxdA, qydA, qzdA, qqdA, m2);
        f2 dA23 = PKD2(x4.zw, y4.zw, z4.zw, k4.zw, qxdA, qydA, qzdA, qqdA, m2);
        f2 dB01 = PKD2(x4.xy, y4.xy, z4.xy, k4.xy, qxdB, qydB, qzdB, qqdB, m2);
        f2 dB23 = PKD2(x4.zw, y4.zw, z4.zw, k4.zw, qxdB, qydB, qzdB, qqdB, m2);
        INS(A, dA01.x, jb);     INS(A, dA01.y, jb + 1);
        INS(A, dA23.x, jb + 2); INS(A, dA23.y, jb + 3);
        INS(B, dB01.x, jb);     INS(B, dB01.y, jb + 1);
        INS(B, dB23.x, jb + 2); INS(B, dB23.y, jb + 3);
    }

    pd[w][lane][0] = b0A; pd[w][lane][1] = b1A; pd[w][lane][2] = b2A;
    pi[w][lane][0] = i0A; pi[w][lane][1] = i1A; pi[w][lane][2] = i2A;
    pd[w][64 + lane][0] = b0B; pd[w][64 + lane][1] = b1B; pd[w][64 + lane][2] = b2B;
    pi[w][64 + lane][0] = i0B; pi[w][64 + lane][1] = i1B; pi[w][64 + lane][2] = i2B;
    __syncthreads();

    if (tid < 128) {
        float m0 = 3.4e38f, m1 = 3.4e38f, m2s = 3.4e38f;
        int   j0 = 0, j1 = 0, j2 = 0;
        #pragma unroll
        for (int c = 0; c < 8; ++c) {
            #pragma unroll
            for (int s = 0; s < 3; ++s) {
                float d = pd[c][tid][s];
                int   i = pi[c][tid][s];
                if (d < m2s) {
                    bool c0 = d < m0, c1 = d < m1;
                    m2s = c1 ? m1 : d;               j2 = c1 ? j1 : i;
                    m1 = c0 ? m0 : (c1 ? d : m1);    j1 = c0 ? j0 : (c1 ? i : j1);
                    m0 = c0 ? d : m0;                j0 = c0 ? i  : j0;
                }
            }
        }
        // weights: mirror reference op order (R8-validated, packed store)
        float d0f = fmaxf(m0, 1e-10f), d1f = fmaxf(m1, 1e-10f), d2f = fmaxf(m2s, 1e-10f);
        float v0 = __fdiv_rn(1.0f, d0f), v1 = __fdiv_rn(1.0f, d1f), v2 = __fdiv_rn(1.0f, d2f);
        float s  = __fadd_rn(__fadd_rn(v0, v1), v2);
        const size_t g = (size_t)b * N1 + n0 + tid;
        *(int4*)  &nn_idx[g * 4] = make_int4(j0, j1, j2, 0);
        *(float4*)&nn_w  [g * 4] = make_float4(__fdiv_rn(v0, s), __fdiv_rn(v1, s),
                                               __fdiv_rn(v2, s), 0.0f);
    }

    // Folded qfeat copy (validated float4 stream; rides knn's idle HBM).
    const float4* qsrc = (const float4*)(qfeat + (size_t)b * C1 * N1);
    float4*       qdst = (float4*)(out + (size_t)b * CO * N1 + (size_t)C2 * N1);
    #pragma unroll
    for (int k = 0; k < 16; ++k) {
        const size_t r = (size_t)tile * 8192 + (size_t)k * 512 + tid;
        qdst[r] = qsrc[r];
    }
}

// ---------------------------------------------------------------------------
// Interp (R9/R10-validated verbatim). Block = (batch, 4-channel group);
// 4 channels staged as float4-per-key in LDS; gather = 3 ds_read_b128;
// nn loads coalesced int4/float4; fma order validated.
// ---------------------------------------------------------------------------
__global__ __launch_bounds__(256) void interp4(
    const float* __restrict__ kfeat,  // (B, C2, N2)
    const int*   __restrict__ nn_idx, // packed stride-4
    const float* __restrict__ nn_w,   // packed stride-4
    float* __restrict__ out)          // (B, CO, N1)
{
    __shared__ __align__(16) float4 skf[N2];   // 32 KB
    const int b     = blockIdx.x & 7;       // XCD-pinned batch
    const int cg    = blockIdx.x >> 3;      // 0..127
    const int cbase = cg * CCH;
    const int tid   = threadIdx.x;

    const float* kf = kfeat + (size_t)b * C2 * N2 + (size_t)cbase * N2;
    for (int j = tid; j < N2; j += 256) {
        skf[j] = make_float4(kf[j], kf[N2 + j], kf[2 * N2 + j], kf[3 * N2 + j]);
    }
    __syncthreads();

    const int*   ib = nn_idx + (size_t)b * N1 * 4;
    const float* wb = nn_w   + (size_t)b * N1 * 4;
    float* ob = out + (size_t)b * CO * N1;

    #pragma unroll 4
    for (int t = 0; t < N1 / 256; ++t) {
        const int n = t * 256 + tid;
        const int4   iv = *(const int4*)  &ib[(size_t)n * 4];
        const float4 wv = *(const float4*)&wb[(size_t)n * 4];
        const float4 f0 = skf[iv.x];
        const float4 f1 = skf[iv.y];
        const float4 f2v = skf[iv.z];
        ob[(size_t)(cbase + 0) * N1 + n] =
            fmaf(wv.z, f2v.x, fmaf(wv.y, f1.x, __fmul_rn(wv.x, f0.x)));
        ob[(size_t)(cbase + 1) * N1 + n] =
            fmaf(wv.z, f2v.y, fmaf(wv.y, f1.y, __fmul_rn(wv.x, f0.y)));
        ob[(size_t)(cbase + 2) * N1 + n] =
            fmaf(wv.z, f2v.z, fmaf(wv.y, f1.z, __fmul_rn(wv.x, f0.z)));
        ob[(size_t)(cbase + 3) * N1 + n] =
            fmaf(wv.z, f2v.w, fmaf(wv.y, f1.w, __fmul_rn(wv.x, f0.w)));
    }
}

extern "C" void kernel_launch(void* const* d_in, const int* in_sizes, int n_in,
                              void* d_out, int out_size, void* d_ws, size_t ws_size,
                              hipStream_t stream) {
    const float* qxyz  = (const float*)d_in[0];
    const float* kxyz  = (const float*)d_in[1];
    const float* qfeat = (const float*)d_in[2];
    const float* kfeat = (const float*)d_in[3];
    float* out = (float*)d_out;

    float*  ws     = (float*)d_ws;
    float4* keys4  = (float4*)ws;                                // 65536 f
    int*    nn_idx = (int*)(ws + (size_t)4 * NB * N2);           // 262144 i
    float*  nn_w   = ws + (size_t)4 * NB * N2 + (size_t)4 * NB * N1;

    pack_keys<<<NB * (N2 / 256), 256, 0, stream>>>(kxyz, keys4);
    knn_scan<<<NB * (N1 / 128), 512, 0, stream>>>(qxyz, keys4, qfeat,
                                                  nn_idx, nn_w, out);
    interp4<<<NB * (C2 / CCH), 256, 0, stream>>>(kfeat, nn_idx, nn_w, out);
}